// Round 10
// baseline (450.661 us; speedup 1.0000x reference)
//
#include <hip/hip_runtime.h>

typedef short short8 __attribute__((ext_vector_type(8)));
typedef float floatx4 __attribute__((ext_vector_type(4)));

#define LEAKY(v) ((v) >= 0.0f ? (v) : 0.01f * (v))

constexpr int D = 256;  // in = hid = out = 256

__device__ __forceinline__ short f2bf(float x) {
  unsigned u = __float_as_uint(x);
  u += 0x7fffu + ((u >> 16) & 1u);  // RNE (finite inputs)
  return (short)(u >> 16);
}
__device__ __forceinline__ float bf2f(short s) {
  return __uint_as_float(((unsigned)(unsigned short)s) << 16);
}

#define AS1 __attribute__((address_space(1)))
#define AS3 __attribute__((address_space(3)))

__device__ __forceinline__ void gload_lds16(const void* g, void* lds) {
  __builtin_amdgcn_global_load_lds((const AS1 void*)g, (AS3 void*)lds, 16, 0, 0);
}

// ---- W transpose+convert: Wt[n][k] = bf16(Wsrc[k][n]), 3 matrices ----------
__global__ void transpose_w(const float* __restrict__ W1,
                            const float* __restrict__ W2,
                            const float* __restrict__ Wl,
                            short* __restrict__ Wt) {
  __shared__ float t[32][33];
  const float* src = (blockIdx.z == 0) ? W1 : (blockIdx.z == 1) ? W2 : Wl;
  short* dst = Wt + (size_t)blockIdx.z * D * D;
  int tx = threadIdx.x, ty = threadIdx.y;
  t[ty][tx] = src[(size_t)(blockIdx.y * 32 + ty) * D + blockIdx.x * 32 + tx];
  __syncthreads();
  dst[(size_t)(blockIdx.x * 32 + ty) * D + blockIdx.y * 32 + tx] =
      f2bf(t[tx][ty]);
}

// ---- m97-style tiled GEMM: 128x128 tile, BK=64, 4 waves, single-buffer -----
// Non-persistent: grid = ceil(M/128) x 2 col-tiles, 4 K-steps per block,
// 2 barriers per K-step; ~3 blocks/CU interleave to cover the stage drains
// (the r5-r9 persistent 8-wave designs could not host 2 blocks at 140 total
// regs -> every drain idled the CU; MfmaUtil pinned at 7%). Keeps the two
// locally-proven pieces: (1) fragment-ordered LDS for BOTH A and B (slot =
// 1KB consumed verbatim as one MFMA operand; gload_lds linear dst; 0 bank
// conflicts measured) and (2) swapped-operand MFMA epilogue with packed
// stores. A_F32: r9's raw-f32 staging + transient convert at frag read.
// Per wave (wr=w>>1, wc=w&1): rows wr*64+i*16+lm, cols wc*64+j*16+q*4.
template <bool A_F32, bool ADD_ROW, bool FINAL>
__global__ __launch_bounds__(256, 3) void gemm_tile(
    const void* __restrict__ Avoid, const short* __restrict__ Wt,
    const float* __restrict__ R, const int* __restrict__ batch,
    const float* __restrict__ bias, void* __restrict__ Cvoid, int M) {
  constexpr int ABYTES = A_F32 ? 32768 : 16384;
  __shared__ __align__(16) char As[ABYTES];  // 16 frags (kk,wr,i), 1/2KB each
  __shared__ __align__(16) char Bs[16384];   // 16 frags (kk,wc,j), 1KB each
  const int tid = threadIdx.x;
  const int l = tid & 63, w = tid >> 6, lm = l & 15, q = l >> 4;
  const int wr = w >> 1, wc = w & 1;
  const int rowBase = (blockIdx.x >> 1) * 128;
  const int colTile = (blockIdx.x & 1) * 128;

  floatx4 acc[4][4];
#pragma unroll
  for (int i = 0; i < 4; i++)
#pragma unroll
    for (int j = 0; j < 4; j++) acc[i][j] = (floatx4){0.f, 0.f, 0.f, 0.f};

  for (int k0 = 0; k0 < 256; k0 += 64) {
    // ---- stage A tile (128 rows x 64 k), fragment-ordered ----
    if (A_F32) {
#pragma unroll
      for (int r = 0; r < 8; r++) {
        const int c = r * 4 + w;               // 0..31, wave-uniform
        const int s = c >> 1, h = c & 1;       // slot, 16B-half
        const int kk = s >> 3, ar = (s >> 2) & 1, i = s & 3;
        int grow = rowBase + ar * 64 + i * 16 + lm;
        grow = grow < M ? grow : M - 1;        // clamp tail (stores guarded)
        const char* src = (const char*)Avoid + (size_t)grow * 1024 + k0 * 4 +
                          kk * 128 + q * 32 + h * 16;
        gload_lds16(src, As + s * 2048 + h * 1024);
      }
    } else {
#pragma unroll
      for (int r = 0; r < 4; r++) {
        const int c = r * 4 + w;               // slot 0..15, wave-uniform
        const int kk = c >> 3, ar = (c >> 2) & 1, i = c & 3;
        int grow = rowBase + ar * 64 + i * 16 + lm;
        grow = grow < M ? grow : M - 1;
        const char* src = (const char*)Avoid + (size_t)grow * 512 + k0 * 2 +
                          kk * 64 + q * 16;
        gload_lds16(src, As + c * 1024);
      }
    }
    // ---- stage B tile (128 cols x 64 k) from Wt (n-major), frag-ordered ----
#pragma unroll
    for (int r = 0; r < 4; r++) {
      const int c = r * 4 + w;
      const int kk = c >> 3, bc = (c >> 2) & 1, j = c & 3;
      const int gn = colTile + bc * 64 + j * 16 + lm;  // < 256 always
      const char* src =
          (const char*)Wt + (size_t)gn * 512 + k0 * 2 + kk * 64 + q * 16;
      gload_lds16(src, Bs + c * 1024);
    }
    __syncthreads();  // drain gload_lds; tiles visible

    // ---- compute: lane-linear frag reads, swapped-operand MFMA ----
#pragma unroll
    for (int kk = 0; kk < 2; kk++) {
      short8 a[4], b[4];
#pragma unroll
      for (int i = 0; i < 4; i++) {
        if (A_F32) {
          const int s = kk * 8 + wr * 4 + i;
          float4 lo = *(const float4*)(As + s * 2048 + l * 16);
          float4 hi = *(const float4*)(As + s * 2048 + 1024 + l * 16);
          short8 sv;
          sv[0] = f2bf(lo.x); sv[1] = f2bf(lo.y); sv[2] = f2bf(lo.z); sv[3] = f2bf(lo.w);
          sv[4] = f2bf(hi.x); sv[5] = f2bf(hi.y); sv[6] = f2bf(hi.z); sv[7] = f2bf(hi.w);
          a[i] = sv;
        } else {
          a[i] = *(const short8*)(As + (kk * 8 + wr * 4 + i) * 1024 + l * 16);
        }
      }
#pragma unroll
      for (int j = 0; j < 4; j++)
        b[j] = *(const short8*)(Bs + (kk * 8 + wc * 4 + j) * 1024 + l * 16);
#pragma unroll
      for (int i = 0; i < 4; i++)
#pragma unroll
        for (int j = 0; j < 4; j++)
          acc[i][j] = __builtin_amdgcn_mfma_f32_16x16x32_bf16(b[j], a[i],
                                                              acc[i][j], 0, 0, 0);
    }
    __syncthreads();  // protect LDS before next K-step overwrites
  }

  // ---- epilogue: lane holds row wr*64+i*16+lm, cols wc*64+j*16+q*4 .. +3 ----
#pragma unroll
  for (int i = 0; i < 4; i++) {
    const int row = rowBase + wr * 64 + i * 16 + lm;
    if (row < M) {
      int rb = 0;
      if (ADD_ROW) rb = batch[row];
#pragma unroll
      for (int j = 0; j < 4; j++) {
        const int col0 = colTile + wc * 64 + j * 16 + q * 4;
        float c0 = acc[i][j][0], c1 = acc[i][j][1], c2 = acc[i][j][2],
              c3 = acc[i][j][3];
        if (ADD_ROW) {
          float4 rv = *(const float4*)(R + (size_t)rb * D + col0);
          c0 += rv.x; c1 += rv.y; c2 += rv.z; c3 += rv.w;
        }
        if (!FINAL) {
          uint2 o;
          o.x = (unsigned)(unsigned short)f2bf(c0) |
                ((unsigned)(unsigned short)f2bf(c1) << 16);
          o.y = (unsigned)(unsigned short)f2bf(c2) |
                ((unsigned)(unsigned short)f2bf(c3) << 16);
          *(uint2*)((short*)Cvoid + (size_t)row * D + col0) = o;
        } else {
          float4 bv = *(const float4*)(bias + col0);
          c0 += bv.x; c1 += bv.y; c2 += bv.z; c3 += bv.w;
          c0 = LEAKY(c0); c1 = LEAKY(c1); c2 = LEAKY(c2); c3 = LEAKY(c3);
          float4 o = {c0, c1, c2, c3};
          *(float4*)((float*)Cvoid + (size_t)row * D + col0) = o;
        }
      }
    }
  }
}

// ---------------- CSR build --------------------------------------------------
__global__ void count_dst(const int* __restrict__ dst, int* __restrict__ offs,
                          int E) {
  int e = blockIdx.x * 256 + threadIdx.x;
  if (e < E) atomicAdd(&offs[dst[e]], 1);
}

__global__ void scan_blocks(int* __restrict__ offs, int* __restrict__ bsums,
                            int n) {
  __shared__ int tmp[256];
  int i = blockIdx.x * 256 + threadIdx.x;
  int v = (i < n) ? offs[i] : 0;
  tmp[threadIdx.x] = v;
  __syncthreads();
  for (int off = 1; off < 256; off <<= 1) {
    int t = (threadIdx.x >= off) ? tmp[threadIdx.x - off] : 0;
    __syncthreads();
    tmp[threadIdx.x] += t;
    __syncthreads();
  }
  if (i < n) offs[i] = tmp[threadIdx.x] - v;
  if (threadIdx.x == 255) bsums[blockIdx.x] = tmp[255];
}

__global__ void scan_sums(int* __restrict__ bs, int nb) {
  __shared__ int tmp[1024];
  int v = (threadIdx.x < nb) ? bs[threadIdx.x] : 0;
  tmp[threadIdx.x] = v;
  __syncthreads();
  for (int off = 1; off < 1024; off <<= 1) {
    int t = (threadIdx.x >= off) ? tmp[threadIdx.x - off] : 0;
    __syncthreads();
    tmp[threadIdx.x] += t;
    __syncthreads();
  }
  if (threadIdx.x < nb) bs[threadIdx.x] = tmp[threadIdx.x] - v;
}

__global__ void add_offsets(int* __restrict__ offs, const int* __restrict__ bs,
                            int n, int* __restrict__ cursor) {
  int i = blockIdx.x * 256 + threadIdx.x;
  if (i < n) {
    int o = offs[i] + bs[blockIdx.x];
    offs[i] = o;
    cursor[i] = o;
  }
}

__global__ void fill_buckets(const int* __restrict__ src,
                             const int* __restrict__ dst,
                             const float* __restrict__ vals,
                             int* __restrict__ cursor, int* __restrict__ esrc,
                             float* __restrict__ ew, int E) {
  int e = blockIdx.x * 256 + threadIdx.x;
  if (e < E) {
    int p = atomicAdd(&cursor[dst[e]], 1);
    esrc[p] = src[e];
    ew[p] = vals[e];
  }
}

// ---- gather agg, 2 edges/wave: out[n] = bf16(leaky(sum w*H[src] + bias)) ---
__global__ __launch_bounds__(256) void aggregate_bf(
    const short* __restrict__ H, const int* __restrict__ offs,
    const int* __restrict__ esrc, const float* __restrict__ ew,
    const float* __restrict__ bias, short* __restrict__ out, int N, int E) {
  int node = blockIdx.x * 4 + (threadIdx.x >> 6);
  if (node >= N) return;
  const int lane = threadIdx.x & 63;
  const int half = lane >> 5, li = lane & 31;
  int beg = offs[node];
  int end = (node == N - 1) ? E : offs[node + 1];
  float a0 = 0.f, a1 = 0.f, a2 = 0.f, a3 = 0.f, a4 = 0.f, a5 = 0.f,
        a6 = 0.f, a7 = 0.f;
  for (int i = beg; i < end; i += 2) {
    const int idx = i + half;
    const bool v = idx < end;
    int s = esrc[v ? idx : i];
    float wv = v ? ew[idx] : 0.f;
    uint4 pk = *(const uint4*)(H + (size_t)s * D + li * 8);  // 8 bf16
    a0 += wv * bf2f((short)(pk.x & 0xffff));
    a1 += wv * bf2f((short)(pk.x >> 16));
    a2 += wv * bf2f((short)(pk.y & 0xffff));
    a3 += wv * bf2f((short)(pk.y >> 16));
    a4 += wv * bf2f((short)(pk.z & 0xffff));
    a5 += wv * bf2f((short)(pk.z >> 16));
    a6 += wv * bf2f((short)(pk.w & 0xffff));
    a7 += wv * bf2f((short)(pk.w >> 16));
  }
  // combine the two 32-lane halves (lane l <-> l+32)
  a0 += __shfl_xor(a0, 32); a1 += __shfl_xor(a1, 32);
  a2 += __shfl_xor(a2, 32); a3 += __shfl_xor(a3, 32);
  a4 += __shfl_xor(a4, 32); a5 += __shfl_xor(a5, 32);
  a6 += __shfl_xor(a6, 32); a7 += __shfl_xor(a7, 32);
  if (half == 0) {
    float4 b0 = *(const float4*)(bias + li * 8);
    float4 b1 = *(const float4*)(bias + li * 8 + 4);
    a0 = LEAKY(a0 + b0.x); a1 = LEAKY(a1 + b0.y);
    a2 = LEAKY(a2 + b0.z); a3 = LEAKY(a3 + b0.w);
    a4 = LEAKY(a4 + b1.x); a5 = LEAKY(a5 + b1.y);
    a6 = LEAKY(a6 + b1.z); a7 = LEAKY(a7 + b1.w);
    uint4 o;
    o.x = (unsigned)(unsigned short)f2bf(a0) |
          ((unsigned)(unsigned short)f2bf(a1) << 16);
    o.y = (unsigned)(unsigned short)f2bf(a2) |
          ((unsigned)(unsigned short)f2bf(a3) << 16);
    o.z = (unsigned)(unsigned short)f2bf(a4) |
          ((unsigned)(unsigned short)f2bf(a5) << 16);
    o.w = (unsigned)(unsigned short)f2bf(a6) |
          ((unsigned)(unsigned short)f2bf(a7) << 16);
    *(uint4*)(out + (size_t)node * D + li * 8) = o;
  }
}

// ---- fused root gemms: blocks [0,B) -> R1, [B,2B) -> R2 --------------------
__global__ void root_both(const float* __restrict__ X,
                          const int* __restrict__ root_idx,
                          const float* __restrict__ W2, float* __restrict__ R1,
                          const short* __restrict__ H,
                          const int* __restrict__ offs,
                          const int* __restrict__ esrc,
                          const float* __restrict__ ew,
                          const float* __restrict__ b1,
                          const float* __restrict__ Wl, float* __restrict__ R2,
                          int N, int E, int B) {
  __shared__ float a[D];
  int j = threadIdx.x;
  if ((int)blockIdx.x < B) {
    int b = blockIdx.x;
    int r = root_idx[b];
    a[j] = LEAKY(X[(size_t)r * D + j]);
    __syncthreads();
    float acc = 0.f;
#pragma unroll 8
    for (int k = 0; k < D; k++) acc += a[k] * W2[(size_t)(D + k) * D + j];
    R1[b * D + j] = acc;
  } else {
    int b = blockIdx.x - B;
    int r = root_idx[b];
    int beg = offs[r], end = (r == N - 1) ? E : offs[r + 1];
    float acc = b1[j];
    for (int e = beg; e < end; e++)
      acc += ew[e] * bf2f(H[(size_t)esrc[e] * D + j]);
    a[j] = acc;
    __syncthreads();
    float s = 0.f;
#pragma unroll 8
    for (int k = 0; k < D; k++) s += a[k] * Wl[(size_t)(D + k) * D + j];
    R2[b * D + j] = s;
  }
}

extern "C" void kernel_launch(void* const* d_in, const int* in_sizes, int n_in,
                              void* d_out, int out_size, void* d_ws,
                              size_t ws_size, hipStream_t stream) {
  const float* features = (const float*)d_in[0];  // [N,256]
  const float* values   = (const float*)d_in[1];  // [E]
  const float* W1 = (const float*)d_in[2];        // [256,256]
  const float* b1 = (const float*)d_in[3];        // [256]
  const float* W2 = (const float*)d_in[4];        // [512,256]
  const float* b2 = (const float*)d_in[5];        // [256]
  const float* Wl = (const float*)d_in[6];        // [512,256]
  const float* bl = (const float*)d_in[7];        // [256]
  const int* adjs = (const int*)d_in[8];          // [2,E]
  const int* batch = (const int*)d_in[9];         // [N]
  const int* root_idx = (const int*)d_in[10];     // [B]

  const int N = in_sizes[0] / D;
  const int E = in_sizes[1];
  const int B = in_sizes[10];
  const int* srcI = adjs;
  const int* dstI = adjs + E;

  // workspace layout
  short* bf0 = (short*)d_ws;            // h0_bf, then h2_bf   [N*256]
  short* bf1 = bf0 + (size_t)N * D;     // a1_bf, then a2_bf   [N*256]
  short* Wt = bf1 + (size_t)N * D;      // 3 x [256,256] bf16 (n-major)
  float* R1 = (float*)(Wt + (size_t)3 * D * D);  // [B,256]
  float* R2 = R1 + (size_t)B * D;                // [B,256]
  float* ew = R2 + (size_t)B * D;                // [E]
  int* offs = (int*)(ew + E);                    // [N]
  int* cursor = offs + N;                        // [N]
  int* esrc = cursor + N;                        // [E]
  int* bsums = esrc + E;                         // [<=1024]

  const int nb = (N + 255) / 256;  // 391 <= 1024

  // ---- build dst-CSR (reused by both aggregations + root2) ----
  hipMemsetAsync(offs, 0, (size_t)N * sizeof(int), stream);
  count_dst<<<(E + 255) / 256, 256, 0, stream>>>(dstI, offs, E);
  scan_blocks<<<nb, 256, 0, stream>>>(offs, bsums, N);
  scan_sums<<<1, 1024, 0, stream>>>(bsums, nb);
  add_offsets<<<nb, 256, 0, stream>>>(offs, bsums, N, cursor);
  fill_buckets<<<(E + 255) / 256, 256, 0, stream>>>(srcI, dstI, values, cursor,
                                                    esrc, ew, E);

  // ---- weights -> bf16, transposed to [n][k] ----
  transpose_w<<<dim3(8, 8, 3), dim3(32, 32), 0, stream>>>(W1, W2, Wl, Wt);

  const int ggrid = ((N + 127) / 128) * 2;  // 782 row-tiles x 2 col-tiles
  const int aggGrid = (N + 3) / 4;

  // 1) h0 = features @ W1           (fp32 in, fused convert, bf16 out)
  gemm_tile<true, false, false><<<ggrid, 256, 0, stream>>>(
      features, Wt, nullptr, nullptr, nullptr, bf0, N);

  // 2) a1 = leaky(segsum(w*h0) + b1)  (bf16)
  aggregate_bf<<<aggGrid, 256, 0, stream>>>(bf0, offs, esrc, ew, b1, bf1, N, E);

  // 3) R1, R2 in one launch (root2 recomputes pre-leaky agg1 rows from CSR)
  root_both<<<2 * B, 256, 0, stream>>>(features, root_idx, W2, R1, bf0, offs,
                                       esrc, ew, b1, Wl, R2, N, E, B);

  // 4) h2 = a1 @ W2_top + R1[batch]   (bf16 in/out; overwrites h0 after root)
  gemm_tile<false, true, false><<<ggrid, 256, 0, stream>>>(
      bf1, Wt + (size_t)D * D, R1, batch, nullptr, bf0, N);

  // 5) a2 = leaky(segsum(w*h2) + b2)  (bf16)
  aggregate_bf<<<aggGrid, 256, 0, stream>>>(bf0, offs, esrc, ew, b2, bf1, N, E);

  // 6) out = leaky(a2 @ Wl_top + R2[batch] + bl)  (fp32 out)
  gemm_tile<false, true, true><<<ggrid, 256, 0, stream>>>(
      bf1, Wt + (size_t)2 * D * D, R2, batch, bl, (float*)d_out, N);
}